// Round 1
// baseline (649.825 us; speedup 1.0000x reference)
//
#include <hip/hip_runtime.h>
#include <hip/hip_bf16.h>

// Problem constants
#define N_USER 55485
#define N_ITEM 5986
#define NN     61471        // total nodes
#define NE     1500000      // edges

// ---------------------------------------------------------------------------
// CSR build
// ---------------------------------------------------------------------------
__global__ void degree_kernel(const int* __restrict__ dst, int* __restrict__ deg) {
    for (int e = blockIdx.x * blockDim.x + threadIdx.x; e < NE;
         e += gridDim.x * blockDim.x)
        atomicAdd(&deg[dst[e]], 1);
}

// Single-block exclusive scan over NN degrees -> row_ptr[N+1], cursor[i]=row_ptr[i]
__global__ void scan_kernel(const int* __restrict__ deg, int* __restrict__ row_ptr,
                            int* __restrict__ cursor) {
    __shared__ int wsum[16];
    __shared__ int woff[17];
    __shared__ int s_run;
    const int t = threadIdx.x;
    const int lane = t & 63, wid = t >> 6;
    if (t == 0) s_run = 0;
    __syncthreads();
    for (int base = 0; base < NN; base += 1024) {
        int i = base + t;
        int v = (i < NN) ? deg[i] : 0;
        int x = v;
        #pragma unroll
        for (int off = 1; off < 64; off <<= 1) {
            int y = __shfl_up(x, off, 64);
            if (lane >= off) x += y;
        }
        if (lane == 63) wsum[wid] = x;
        __syncthreads();
        if (t == 0) {
            int acc = s_run;
            #pragma unroll
            for (int w = 0; w < 16; ++w) { woff[w] = acc; acc += wsum[w]; }
            s_run = acc;
        }
        __syncthreads();
        if (i < NN) {
            int incl = woff[wid] + x;
            row_ptr[i + 1] = incl;
            cursor[i] = incl - v;   // exclusive prefix
        }
    }
    if (t == 0) row_ptr[0] = 0;
}

__global__ void fill_kernel(const int* __restrict__ src, const int* __restrict__ dst,
                            int* __restrict__ cursor, int* __restrict__ csr) {
    for (int e = blockIdx.x * blockDim.x + threadIdx.x; e < NE;
         e += gridDim.x * blockDim.x) {
        int p = atomicAdd(&cursor[dst[e]], 1);
        csr[p] = src[e];
    }
}

// ---------------------------------------------------------------------------
// GEMM: out[N, 2*halfCols] = X[N,128] @ [Wa | Wb]   (fp32, tiled 64x64)
// mode 0: X = concat(user, item) read from xa/xb; mode 1: X = xa
// ---------------------------------------------------------------------------
__global__ __launch_bounds__(256) void gemm_kernel(
    const float* __restrict__ xa, const float* __restrict__ xb,
    const float* __restrict__ Wa, const float* __restrict__ Wb,
    float* __restrict__ out, int halfCols, int mode)
{
    __shared__ float Xs[128][64];   // [k][r]  (transposed X tile)
    __shared__ float Ws[128][64];   // [k][c]
    const int t = threadIdx.x;
    const int rowBase = blockIdx.x * 64;
    const int c0g = blockIdx.y * 64;                  // col offset in combined output
    const float* Wsrc; int cb;
    if (c0g < halfCols) { Wsrc = Wa; cb = c0g; }
    else               { Wsrc = Wb; cb = c0g - halfCols; }

    // ---- load X tile (transposed into LDS) ----
    {
        int r  = t >> 2;                 // 0..63
        int k0 = (t & 3) * 32;           // 0,32,64,96
        int gr = rowBase + r;
        const float* xrow = nullptr;
        if (gr < NN) {
            if (mode == 0)
                xrow = (gr < N_USER) ? (xa + (size_t)gr * 128)
                                     : (xb + (size_t)(gr - N_USER) * 128);
            else
                xrow = xa + (size_t)gr * 128;
        }
        #pragma unroll
        for (int j = 0; j < 8; ++j) {
            int k = k0 + j * 4;
            float4 v = xrow ? *(const float4*)(xrow + k) : make_float4(0.f, 0.f, 0.f, 0.f);
            Xs[k + 0][r] = v.x; Xs[k + 1][r] = v.y;
            Xs[k + 2][r] = v.z; Xs[k + 3][r] = v.w;
        }
    }
    // ---- load W tile ----
    {
        int k  = t >> 1;                 // 0..127
        int c0 = (t & 1) * 32;           // 0,32
        const float* wrow = Wsrc + (size_t)k * halfCols + cb;
        #pragma unroll
        for (int j = 0; j < 8; ++j)
            *(float4*)&Ws[k][c0 + j * 4] = *(const float4*)(wrow + c0 + j * 4);
    }
    __syncthreads();

    const int tr = t >> 4, tc = t & 15;
    const int r0 = tr * 4, c0 = tc * 4;
    float acc[4][4] = {};
    #pragma unroll 4
    for (int k = 0; k < 128; ++k) {
        float4 xv = *(const float4*)&Xs[k][r0];
        float4 wv = *(const float4*)&Ws[k][c0];
        float ax[4] = {xv.x, xv.y, xv.z, xv.w};
        float aw[4] = {wv.x, wv.y, wv.z, wv.w};
        #pragma unroll
        for (int i = 0; i < 4; ++i)
            #pragma unroll
            for (int j = 0; j < 4; ++j)
                acc[i][j] += ax[i] * aw[j];
    }

    const int stride = 2 * halfCols;
    #pragma unroll
    for (int i = 0; i < 4; ++i) {
        int gr = rowBase + r0 + i;
        if (gr < NN)
            *(float4*)&out[(size_t)gr * stride + c0g + c0] =
                make_float4(acc[i][0], acc[i][1], acc[i][2], acc[i][3]);
    }
}

// ---------------------------------------------------------------------------
// Aggregation layer 1: x1[i] = leaky( mean_j(buf1[j,0:128]) + b1 + buf1[i,128:256] )
// one wave per node, 2 cols/lane
// ---------------------------------------------------------------------------
__global__ __launch_bounds__(256) void agg1_kernel(
    const float* __restrict__ buf1, const int* __restrict__ row_ptr,
    const int* __restrict__ csr, const float* __restrict__ b1,
    float* __restrict__ x1)
{
    int node = blockIdx.x * 4 + (threadIdx.x >> 6);
    if (node >= NN) return;
    int lane = threadIdx.x & 63;
    int beg = row_ptr[node], end = row_ptr[node + 1];
    float sx = 0.f, sy = 0.f;
    for (int p = beg; p < end; ++p) {
        int s = csr[p];
        float2 v = *(const float2*)(buf1 + (size_t)s * 256 + lane * 2);
        sx += v.x; sy += v.y;
    }
    float inv = 1.0f / fmaxf((float)(end - beg), 1.0f);
    float2 r  = *(const float2*)(buf1 + (size_t)node * 256 + 128 + lane * 2);
    float2 bb = *(const float2*)(b1 + lane * 2);
    float o0 = sx * inv + bb.x + r.x;
    float o1 = sy * inv + bb.y + r.y;
    o0 = (o0 > 0.f) ? o0 : 0.01f * o0;
    o1 = (o1 > 0.f) ? o1 : 0.01f * o1;
    *(float2*)(x1 + (size_t)node * 128 + lane * 2) = make_float2(o0, o1);
}

// ---------------------------------------------------------------------------
// Aggregation layer 2: out[i] = mean_j(buf2[j,0:64]) + b2 + buf2[i,64:128]
// one wave per node, 1 col/lane
// ---------------------------------------------------------------------------
__global__ __launch_bounds__(256) void agg2_kernel(
    const float* __restrict__ buf2, const int* __restrict__ row_ptr,
    const int* __restrict__ csr, const float* __restrict__ b2,
    float* __restrict__ out)
{
    int node = blockIdx.x * 4 + (threadIdx.x >> 6);
    if (node >= NN) return;
    int lane = threadIdx.x & 63;
    int beg = row_ptr[node], end = row_ptr[node + 1];
    float s = 0.f;
    for (int p = beg; p < end; ++p) {
        int j = csr[p];
        s += buf2[(size_t)j * 128 + lane];
    }
    float inv = 1.0f / fmaxf((float)(end - beg), 1.0f);
    float o = s * inv + b2[lane] + buf2[(size_t)node * 128 + 64 + lane];
    out[(size_t)node * 64 + lane] = o;
}

// ---------------------------------------------------------------------------
extern "C" void kernel_launch(void* const* d_in, const int* in_sizes, int n_in,
                              void* d_out, int out_size, void* d_ws, size_t ws_size,
                              hipStream_t stream) {
    const float* user = (const float*)d_in[0];
    const float* item = (const float*)d_in[1];
    const float* W1l  = (const float*)d_in[2];
    const float* b1   = (const float*)d_in[3];
    const float* W1r  = (const float*)d_in[4];
    const float* W2l  = (const float*)d_in[5];
    const float* b2   = (const float*)d_in[6];
    const float* W2r  = (const float*)d_in[7];
    const int*   edge = (const int*)d_in[8];
    const int* srcIdx = edge;          // edge_index[0]
    const int* dstIdx = edge + NE;     // edge_index[1]
    float* out = (float*)d_out;

    char* ws = (char*)d_ws;
    size_t off = 0;
    auto alloc = [&](size_t bytes) {
        void* p = ws + off;
        off += (bytes + 255) & ~(size_t)255;
        return p;
    };
    int* deg     = (int*)alloc((size_t)NN * 4);
    int* row_ptr = (int*)alloc((size_t)(NN + 1) * 4);
    int* cursor  = (int*)alloc((size_t)NN * 4);
    int* csr     = (int*)alloc((size_t)NE * 4);
    float* buf1  = (float*)alloc((size_t)NN * 256 * 4);  // GEMM1 out [N, 256]
    float* x1    = (float*)alloc((size_t)NN * 128 * 4);  // layer-1 activations
    float* buf2  = buf1;   // alias: buf1 dead after agg1, reuse for GEMM2 out [N,128]

    hipMemsetAsync(deg, 0, (size_t)NN * 4, stream);
    degree_kernel<<<2048, 256, 0, stream>>>(dstIdx, deg);
    scan_kernel<<<1, 1024, 0, stream>>>(deg, row_ptr, cursor);
    fill_kernel<<<2048, 256, 0, stream>>>(srcIdx, dstIdx, cursor, csr);

    // Layer 1: buf1[:,0:128] = X@W1l ; buf1[:,128:256] = X@W1r
    gemm_kernel<<<dim3(961, 4), 256, 0, stream>>>(user, item, W1l, W1r, buf1, 128, 0);
    agg1_kernel<<<(NN + 3) / 4, 256, 0, stream>>>(buf1, row_ptr, csr, b1, x1);

    // Layer 2: buf2[:,0:64] = x1@W2l ; buf2[:,64:128] = x1@W2r
    gemm_kernel<<<dim3(961, 2), 256, 0, stream>>>(x1, nullptr, W2l, W2r, buf2, 64, 1);
    agg2_kernel<<<(NN + 3) / 4, 256, 0, stream>>>(buf2, row_ptr, csr, b2, out);
}

// Round 2
// 530.911 us; speedup vs baseline: 1.2240x; 1.2240x over previous
//
#include <hip/hip_runtime.h>
#include <hip/hip_bf16.h>

// Problem constants
#define N_USER 55485
#define N_ITEM 5986
#define NN     61471        // total nodes
#define NE     1500000      // edges

__device__ __forceinline__ unsigned short f2bf(float f) {
    unsigned u = __float_as_uint(f);
    return (unsigned short)((u + 0x7fffu + ((u >> 16) & 1u)) >> 16);
}
__device__ __forceinline__ float bf_lo(unsigned u) { return __uint_as_float(u << 16); }
__device__ __forceinline__ float bf_hi(unsigned u) { return __uint_as_float(u & 0xffff0000u); }

// ---------------------------------------------------------------------------
// CSR build
// ---------------------------------------------------------------------------
__global__ void degree_kernel(const int* __restrict__ dst, int* __restrict__ deg) {
    for (int e = blockIdx.x * blockDim.x + threadIdx.x; e < NE;
         e += gridDim.x * blockDim.x)
        atomicAdd(&deg[dst[e]], 1);
}

// Single-block exclusive scan over NN degrees -> row_ptr[N+1], cursor[i]=row_ptr[i]
__global__ void scan_kernel(const int* __restrict__ deg, int* __restrict__ row_ptr,
                            int* __restrict__ cursor) {
    __shared__ int wsum[16];
    __shared__ int woff[17];
    __shared__ int s_run;
    const int t = threadIdx.x;
    const int lane = t & 63, wid = t >> 6;
    if (t == 0) s_run = 0;
    __syncthreads();
    for (int base = 0; base < NN; base += 1024) {
        int i = base + t;
        int v = (i < NN) ? deg[i] : 0;
        int x = v;
        #pragma unroll
        for (int off = 1; off < 64; off <<= 1) {
            int y = __shfl_up(x, off, 64);
            if (lane >= off) x += y;
        }
        if (lane == 63) wsum[wid] = x;
        __syncthreads();
        if (t == 0) {
            int acc = s_run;
            #pragma unroll
            for (int w = 0; w < 16; ++w) { woff[w] = acc; acc += wsum[w]; }
            s_run = acc;
        }
        __syncthreads();
        if (i < NN) {
            int incl = woff[wid] + x;
            row_ptr[i + 1] = incl;
            cursor[i] = incl - v;   // exclusive prefix
        }
    }
    if (t == 0) row_ptr[0] = 0;
}

__global__ void fill_kernel(const int* __restrict__ src, const int* __restrict__ dst,
                            int* __restrict__ cursor, int* __restrict__ csr) {
    for (int e = blockIdx.x * blockDim.x + threadIdx.x; e < NE;
         e += gridDim.x * blockDim.x) {
        int p = atomicAdd(&cursor[dst[e]], 1);
        csr[p] = src[e];
    }
}

// ---------------------------------------------------------------------------
// GEMM: out[N, 2*halfCols](bf16) = X[N,128](f32) @ [Wa | Wb]   (tiled 64x64)
// mode 0: X = concat(user, item) read from xa/xb; mode 1: X = xa
// ---------------------------------------------------------------------------
__global__ __launch_bounds__(256) void gemm_kernel(
    const float* __restrict__ xa, const float* __restrict__ xb,
    const float* __restrict__ Wa, const float* __restrict__ Wb,
    unsigned short* __restrict__ out, int halfCols, int mode)
{
    __shared__ float Xs[128][64];   // [k][r]  (transposed X tile)
    __shared__ float Ws[128][64];   // [k][c]
    const int t = threadIdx.x;
    const int rowBase = blockIdx.x * 64;
    const int c0g = blockIdx.y * 64;                  // col offset in combined output
    const float* Wsrc; int cb;
    if (c0g < halfCols) { Wsrc = Wa; cb = c0g; }
    else               { Wsrc = Wb; cb = c0g - halfCols; }

    // ---- load X tile (transposed into LDS) ----
    {
        int r  = t >> 2;                 // 0..63
        int k0 = (t & 3) * 32;           // 0,32,64,96
        int gr = rowBase + r;
        const float* xrow = nullptr;
        if (gr < NN) {
            if (mode == 0)
                xrow = (gr < N_USER) ? (xa + (size_t)gr * 128)
                                     : (xb + (size_t)(gr - N_USER) * 128);
            else
                xrow = xa + (size_t)gr * 128;
        }
        #pragma unroll
        for (int j = 0; j < 8; ++j) {
            int k = k0 + j * 4;
            float4 v = xrow ? *(const float4*)(xrow + k) : make_float4(0.f, 0.f, 0.f, 0.f);
            Xs[k + 0][r] = v.x; Xs[k + 1][r] = v.y;
            Xs[k + 2][r] = v.z; Xs[k + 3][r] = v.w;
        }
    }
    // ---- load W tile ----
    {
        int k  = t >> 1;                 // 0..127
        int c0 = (t & 1) * 32;           // 0,32
        const float* wrow = Wsrc + (size_t)k * halfCols + cb;
        #pragma unroll
        for (int j = 0; j < 8; ++j)
            *(float4*)&Ws[k][c0 + j * 4] = *(const float4*)(wrow + c0 + j * 4);
    }
    __syncthreads();

    const int tr = t >> 4, tc = t & 15;
    const int r0 = tr * 4, c0 = tc * 4;
    float acc[4][4] = {};
    #pragma unroll 4
    for (int k = 0; k < 128; ++k) {
        float4 xv = *(const float4*)&Xs[k][r0];
        float4 wv = *(const float4*)&Ws[k][c0];
        float ax[4] = {xv.x, xv.y, xv.z, xv.w};
        float aw[4] = {wv.x, wv.y, wv.z, wv.w};
        #pragma unroll
        for (int i = 0; i < 4; ++i)
            #pragma unroll
            for (int j = 0; j < 4; ++j)
                acc[i][j] += ax[i] * aw[j];
    }

    const int stride = 2 * halfCols;
    #pragma unroll
    for (int i = 0; i < 4; ++i) {
        int gr = rowBase + r0 + i;
        if (gr < NN) {
            ushort4 w;
            w.x = f2bf(acc[i][0]); w.y = f2bf(acc[i][1]);
            w.z = f2bf(acc[i][2]); w.w = f2bf(acc[i][3]);
            *(ushort4*)&out[(size_t)gr * stride + c0g + c0] = w;
        }
    }
}

// ---------------------------------------------------------------------------
// Aggregation layer 1 (bf16 staging):
//   x1[i] = leaky( mean_j(buf1[j,0:128]) + b1 + buf1[i,128:256] )
// one wave per node, 2 cols/lane (4B/lane), 2 edges per iteration
// ---------------------------------------------------------------------------
__global__ __launch_bounds__(256) void agg1_kernel(
    const unsigned short* __restrict__ buf1, const int* __restrict__ row_ptr,
    const int* __restrict__ csr, const float* __restrict__ b1,
    float* __restrict__ x1)
{
    int node = blockIdx.x * 4 + (threadIdx.x >> 6);
    if (node >= NN) return;
    int lane = threadIdx.x & 63;
    int beg = row_ptr[node], end = row_ptr[node + 1];
    float sx = 0.f, sy = 0.f;
    int p = beg;
    for (; p + 1 < end; p += 2) {
        int s0 = csr[p], s1 = csr[p + 1];
        unsigned u0 = *(const unsigned*)(buf1 + (size_t)s0 * 256 + lane * 2);
        unsigned u1 = *(const unsigned*)(buf1 + (size_t)s1 * 256 + lane * 2);
        sx += bf_lo(u0) + bf_lo(u1);
        sy += bf_hi(u0) + bf_hi(u1);
    }
    if (p < end) {
        int s0 = csr[p];
        unsigned u0 = *(const unsigned*)(buf1 + (size_t)s0 * 256 + lane * 2);
        sx += bf_lo(u0); sy += bf_hi(u0);
    }
    float inv = 1.0f / fmaxf((float)(end - beg), 1.0f);
    unsigned ur = *(const unsigned*)(buf1 + (size_t)node * 256 + 128 + lane * 2);
    float2 bb = *(const float2*)(b1 + lane * 2);
    float o0 = sx * inv + bb.x + bf_lo(ur);
    float o1 = sy * inv + bb.y + bf_hi(ur);
    o0 = (o0 > 0.f) ? o0 : 0.01f * o0;
    o1 = (o1 > 0.f) ? o1 : 0.01f * o1;
    *(float2*)(x1 + (size_t)node * 128 + lane * 2) = make_float2(o0, o1);
}

// ---------------------------------------------------------------------------
// Aggregation layer 2 (bf16 staging): out[i] = mean_j(buf2[j,0:64]) + b2 + buf2[i,64:128]
// one wave per node; two 32-lane halves each take alternate edges (4B/lane)
// ---------------------------------------------------------------------------
__global__ __launch_bounds__(256) void agg2_kernel(
    const unsigned short* __restrict__ buf2, const int* __restrict__ row_ptr,
    const int* __restrict__ csr, const float* __restrict__ b2,
    float* __restrict__ out)
{
    int node = blockIdx.x * 4 + (threadIdx.x >> 6);
    if (node >= NN) return;
    int lane = threadIdx.x & 63;
    int half = lane >> 5, hl = lane & 31;
    int beg = row_ptr[node], end = row_ptr[node + 1];
    float sx = 0.f, sy = 0.f;
    for (int p = beg + half; p < end; p += 2) {
        int j = csr[p];
        unsigned u = *(const unsigned*)(buf2 + (size_t)j * 128 + hl * 2);
        sx += bf_lo(u); sy += bf_hi(u);
    }
    sx += __shfl_xor(sx, 32);
    sy += __shfl_xor(sy, 32);
    if (half == 0) {
        float inv = 1.0f / fmaxf((float)(end - beg), 1.0f);
        unsigned ur = *(const unsigned*)(buf2 + (size_t)node * 128 + 64 + hl * 2);
        float2 bb = *(const float2*)(b2 + hl * 2);
        float o0 = sx * inv + bb.x + bf_lo(ur);
        float o1 = sy * inv + bb.y + bf_hi(ur);
        *(float2*)(out + (size_t)node * 64 + hl * 2) = make_float2(o0, o1);
    }
}

// ---------------------------------------------------------------------------
extern "C" void kernel_launch(void* const* d_in, const int* in_sizes, int n_in,
                              void* d_out, int out_size, void* d_ws, size_t ws_size,
                              hipStream_t stream) {
    const float* user = (const float*)d_in[0];
    const float* item = (const float*)d_in[1];
    const float* W1l  = (const float*)d_in[2];
    const float* b1   = (const float*)d_in[3];
    const float* W1r  = (const float*)d_in[4];
    const float* W2l  = (const float*)d_in[5];
    const float* b2   = (const float*)d_in[6];
    const float* W2r  = (const float*)d_in[7];
    const int*   edge = (const int*)d_in[8];
    const int* srcIdx = edge;          // edge_index[0]
    const int* dstIdx = edge + NE;     // edge_index[1]
    float* out = (float*)d_out;

    char* ws = (char*)d_ws;
    size_t off = 0;
    auto alloc = [&](size_t bytes) {
        void* p = ws + off;
        off += (bytes + 255) & ~(size_t)255;
        return p;
    };
    int* deg     = (int*)alloc((size_t)NN * 4);
    int* row_ptr = (int*)alloc((size_t)(NN + 1) * 4);
    int* cursor  = (int*)alloc((size_t)NN * 4);
    int* csr     = (int*)alloc((size_t)NE * 4);
    unsigned short* buf1 = (unsigned short*)alloc((size_t)NN * 256 * 2); // GEMM1 out bf16 [N,256]
    float* x1    = (float*)alloc((size_t)NN * 128 * 4);  // layer-1 activations (f32)
    unsigned short* buf2 = buf1;   // alias: buf1 dead after agg1; GEMM2 out bf16 [N,128]

    hipMemsetAsync(deg, 0, (size_t)NN * 4, stream);
    degree_kernel<<<2048, 256, 0, stream>>>(dstIdx, deg);
    scan_kernel<<<1, 1024, 0, stream>>>(deg, row_ptr, cursor);
    fill_kernel<<<2048, 256, 0, stream>>>(srcIdx, dstIdx, cursor, csr);

    // Layer 1: buf1[:,0:128] = X@W1l ; buf1[:,128:256] = X@W1r
    gemm_kernel<<<dim3(961, 4), 256, 0, stream>>>(user, item, W1l, W1r, buf1, 128, 0);
    agg1_kernel<<<(NN + 3) / 4, 256, 0, stream>>>(buf1, row_ptr, csr, b1, x1);

    // Layer 2: buf2[:,0:64] = x1@W2l ; buf2[:,64:128] = x1@W2r
    gemm_kernel<<<dim3(961, 2), 256, 0, stream>>>(x1, nullptr, W2l, W2r, buf2, 64, 1);
    agg2_kernel<<<(NN + 3) / 4, 256, 0, stream>>>(buf2, row_ptr, csr, b2, out);
}